// Round 7
// baseline (196.043 us; speedup 1.0000x reference)
//
#include <hip/hip_runtime.h>
#include <hip/hip_bf16.h>

// Q3 unpack: each int32 holds 10 x 3-bit fields at shifts 27,24,...,0.
// Output block k (k=0..9) along dim 0 is ((packed >> (27-3k)) & 7), int32.
//
// k-major phase split: each block handles ONE k-stream for one contiguous
// chunk -> every wave has exactly 1 read stream + 1 write stream (the D2D
// copy profile, 6.3 TB/s), instead of 1+10 interleaved streams. The input
// (67 MB) is re-read 10x but fits entirely in the 256 MB Infinity Cache, so
// re-reads are LLC hits, not HBM. Loads cacheable; stores nontemporal.

typedef int v4i __attribute__((ext_vector_type(4)));

constexpr int TPB = 256;
constexpr int VPT = 8;                 // v4i per thread
constexpr int VPB = TPB * VPT;         // 2048 v4i per block (32 KB)

__global__ __launch_bounds__(256) void q3_unpack_kernel(
    const v4i* __restrict__ in, v4i* __restrict__ out, int stride_vec) {
    const int lane = threadIdx.x & 63;
    const int w = threadIdx.x >> 6;
    const int k = blockIdx.y;
    const int sh = 27 - 3 * k;

    // wave-contiguous: wave w owns v4i range [chunk + w*512, chunk + w*512 + 512)
    const size_t wbase = (size_t)blockIdx.x * VPB + (size_t)w * (64 * VPT) + lane;
    const size_t obase = (size_t)k * (size_t)stride_vec + wbase;

#pragma unroll
    for (int j = 0; j < VPT; ++j) {
        v4i p = in[wbase + (size_t)j * 64];          // cacheable: LLC serves re-reads
        v4i v = (p >> sh) & 7;
        __builtin_nontemporal_store(v, &out[obase + (size_t)j * 64]);
    }
}

extern "C" void kernel_launch(void* const* d_in, const int* in_sizes, int n_in,
                              void* d_out, int out_size, void* d_ws, size_t ws_size,
                              hipStream_t stream) {
    const int* packed = (const int*)d_in[0];
    int* out = (int*)d_out;

    const int n_words = in_sizes[0];     // 4096*4096 = 16,777,216
    const int nvec = n_words / 4;        // 4,194,304 v4i
    const int stride_vec = n_words / 4;  // k-block stride in v4i units

    dim3 grid(nvec / VPB, 10);           // 2048 chunks x 10 k-streams

    q3_unpack_kernel<<<grid, TPB, 0, stream>>>(
        (const v4i*)packed, (v4i*)out, stride_vec);
}